// Round 9
// baseline (442.022 us; speedup 1.0000x reference)
//
#include <hip/hip_runtime.h>

#define CN 128
#define NB 16
#define KS 7
#define PD 3
#define HW 224
#define NTH 256         // 4 waves
#define RPT 8           // output rows per wave
#define TILE_H 32       // 4 waves x 8 rows
#define YTILES 7        // 224/32

#define LW(i) const float w##i = kv[i];

// FMAs for output row Q with explicit weight scalars.
// Window regs r1..r10 hold input cols x0-3 .. x0+6 of the current input row.
#define FMA_QROW(Q, W0,W1,W2,W3,W4,W5,W6) \
  acx##Q = fmaf(W0, r1,  acx##Q); \
  acx##Q = fmaf(W1, r2,  acx##Q); \
  acx##Q = fmaf(W2, r3,  acx##Q); \
  acx##Q = fmaf(W3, r4,  acx##Q); \
  acx##Q = fmaf(W4, r5,  acx##Q); \
  acx##Q = fmaf(W5, r6,  acx##Q); \
  acx##Q = fmaf(W6, r7,  acx##Q); \
  acy##Q = fmaf(W0, r2,  acy##Q); \
  acy##Q = fmaf(W1, r3,  acy##Q); \
  acy##Q = fmaf(W2, r4,  acy##Q); \
  acy##Q = fmaf(W3, r5,  acy##Q); \
  acy##Q = fmaf(W4, r6,  acy##Q); \
  acy##Q = fmaf(W5, r7,  acy##Q); \
  acy##Q = fmaf(W6, r8,  acy##Q); \
  acz##Q = fmaf(W0, r3,  acz##Q); \
  acz##Q = fmaf(W1, r4,  acz##Q); \
  acz##Q = fmaf(W2, r5,  acz##Q); \
  acz##Q = fmaf(W3, r6,  acz##Q); \
  acz##Q = fmaf(W4, r7,  acz##Q); \
  acz##Q = fmaf(W5, r8,  acz##Q); \
  acz##Q = fmaf(W6, r9,  acz##Q); \
  acw##Q = fmaf(W0, r4,  acw##Q); \
  acw##Q = fmaf(W1, r5,  acw##Q); \
  acw##Q = fmaf(W2, r6,  acw##Q); \
  acw##Q = fmaf(W3, r7,  acw##Q); \
  acw##Q = fmaf(W4, r8,  acw##Q); \
  acw##Q = fmaf(W5, r9,  acw##Q); \
  acw##Q = fmaf(W6, r10, acw##Q);

// Weight rows of the symmetric 7x7 (flat p -> param min(p,48-p)):
#define QROW0(Q) FMA_QROW(Q, w0,w1,w2,w3,w4,w5,w6)
#define QROW1(Q) FMA_QROW(Q, w7,w8,w9,w10,w11,w12,w13)
#define QROW2(Q) FMA_QROW(Q, w14,w15,w16,w17,w18,w19,w20)
#define QROW3(Q) FMA_QROW(Q, w21,w22,w23,w24,w23,w22,w21)
#define QROW4(Q) FMA_QROW(Q, w20,w19,w18,w17,w16,w15,w14)
#define QROW5(Q) FMA_QROW(Q, w13,w12,w11,w10,w9,w8,w7)
#define QROW6(Q) FMA_QROW(Q, w6,w5,w4,w3,w2,w1,w0)

// Window for input row gr0+J straight from global (L1/L2-cached), no LDS.
// pl/pc/pr are per-lane column pointers (left-clamped / center / right-clamped).
// Row guard is wave-uniform; edge lanes patched by e0/e55 selects.
#define LOAD_ROW(J) { \
    const int gr_ = gr0 + (J); \
    float4 L_ = z4, C_ = z4, R_ = z4; \
    if (gr_ >= 0 && gr_ < HW) { \
        const int off_ = gr_ * HW; \
        L_ = *reinterpret_cast<const float4*>(pl + off_); \
        C_ = *reinterpret_cast<const float4*>(pc + off_); \
        R_ = *reinterpret_cast<const float4*>(pr + off_); \
    } \
    r1 = e0 ? 0.f : L_.y;  r2 = e0 ? 0.f : L_.z;  r3 = e0 ? 0.f : L_.w; \
    r4 = C_.x; r5 = C_.y; r6 = C_.z; r7 = C_.w; \
    r8 = e55 ? 0.f : R_.x; r9 = e55 ? 0.f : R_.y; r10 = e55 ? 0.f : R_.z; }

// Empirical hipcc law (rounds 1-8, 5 data points): VGPR cap = 256/min_waves_per_EU.
// This kernel's demand is ~145 (32 acc + pipelined row loads). Single-arg
// launch_bounds -> min_waves=1 -> cap 256 -> NO spill; HW co-schedules
// 512/alloc ~= 3 waves/SIMD naturally.
__global__ __launch_bounds__(NTH)
void dwconv7x7_sym(const float* __restrict__ x, const float* __restrict__ kv,
                   float* __restrict__ out) {
    const int bid   = blockIdx.x;
    const int plane = bid / YTILES;
    const int ytile = bid - plane * YTILES;
    const int tid   = threadIdx.x;
    const int wave  = tid >> 6;
    const int lane  = tid & 63;
    if (lane >= 56) return;            // no barriers anywhere: early-exit is safe

    const float* xp = x + (size_t)plane * (HW * HW);
    float* op       = out + (size_t)plane * (HW * HW);

    const int row0 = ytile * TILE_H + wave * RPT;  // first output row of strip
    const int gr0  = row0 - PD;                    // first input row needed

    const int x0 = lane * 4;
    const int xl = (x0 >= 4)   ? x0 - 4 : 0;       // clamped left float4
    const int xr = (x0 <= 216) ? x0 + 4 : 220;     // clamped right float4
    const float* pc = xp + x0;
    const float* pl = xp + xl;
    const float* pr = xp + xr;
    const bool e0  = (lane == 0);
    const bool e55 = (lane == 55);
    const float4 z4 = make_float4(0.f, 0.f, 0.f, 0.f);

    LW(0)  LW(1)  LW(2)  LW(3)  LW(4)  LW(5)  LW(6)  LW(7)  LW(8)  LW(9)
    LW(10) LW(11) LW(12) LW(13) LW(14) LW(15) LW(16) LW(17) LW(18) LW(19)
    LW(20) LW(21) LW(22) LW(23) LW(24)

    float acx0=0.f, acy0=0.f, acz0=0.f, acw0=0.f;
    float acx1=0.f, acy1=0.f, acz1=0.f, acw1=0.f;
    float acx2=0.f, acy2=0.f, acz2=0.f, acw2=0.f;
    float acx3=0.f, acy3=0.f, acz3=0.f, acw3=0.f;
    float acx4=0.f, acy4=0.f, acz4=0.f, acw4=0.f;
    float acx5=0.f, acy5=0.f, acz5=0.f, acw5=0.f;
    float acx6=0.f, acy6=0.f, acz6=0.f, acw6=0.f;
    float acx7=0.f, acy7=0.f, acz7=0.f, acw7=0.f;
    float r1,r2,r3,r4,r5,r6,r7,r8,r9,r10;

    LOAD_ROW(0);  QROW0(0);
    LOAD_ROW(1);  QROW1(0); QROW0(1);
    LOAD_ROW(2);  QROW2(0); QROW1(1); QROW0(2);
    LOAD_ROW(3);  QROW3(0); QROW2(1); QROW1(2); QROW0(3);
    LOAD_ROW(4);  QROW4(0); QROW3(1); QROW2(2); QROW1(3); QROW0(4);
    LOAD_ROW(5);  QROW5(0); QROW4(1); QROW3(2); QROW2(3); QROW1(4); QROW0(5);
    LOAD_ROW(6);  QROW6(0); QROW5(1); QROW4(2); QROW3(3); QROW2(4); QROW1(5); QROW0(6);
    LOAD_ROW(7);  QROW6(1); QROW5(2); QROW4(3); QROW3(4); QROW2(5); QROW1(6); QROW0(7);
    LOAD_ROW(8);  QROW6(2); QROW5(3); QROW4(4); QROW3(5); QROW2(6); QROW1(7);
    LOAD_ROW(9);  QROW6(3); QROW5(4); QROW4(5); QROW3(6); QROW2(7);
    LOAD_ROW(10); QROW6(4); QROW5(5); QROW4(6); QROW3(7);
    LOAD_ROW(11); QROW6(5); QROW5(6); QROW4(7);
    LOAD_ROW(12); QROW6(6); QROW5(7);
    LOAD_ROW(13); QROW6(7);

    *reinterpret_cast<float4*>(op + (row0 + 0) * HW + x0) = make_float4(acx0, acy0, acz0, acw0);
    *reinterpret_cast<float4*>(op + (row0 + 1) * HW + x0) = make_float4(acx1, acy1, acz1, acw1);
    *reinterpret_cast<float4*>(op + (row0 + 2) * HW + x0) = make_float4(acx2, acy2, acz2, acw2);
    *reinterpret_cast<float4*>(op + (row0 + 3) * HW + x0) = make_float4(acx3, acy3, acz3, acw3);
    *reinterpret_cast<float4*>(op + (row0 + 4) * HW + x0) = make_float4(acx4, acy4, acz4, acw4);
    *reinterpret_cast<float4*>(op + (row0 + 5) * HW + x0) = make_float4(acx5, acy5, acz5, acw5);
    *reinterpret_cast<float4*>(op + (row0 + 6) * HW + x0) = make_float4(acx6, acy6, acz6, acw6);
    *reinterpret_cast<float4*>(op + (row0 + 7) * HW + x0) = make_float4(acx7, acy7, acz7, acw7);
}

extern "C" void kernel_launch(void* const* d_in, const int* in_sizes, int n_in,
                              void* d_out, int out_size, void* d_ws, size_t ws_size,
                              hipStream_t stream) {
    const float* x  = (const float*)d_in[0];   // (16,128,224,224) f32
    const float* kv = (const float*)d_in[1];   // (25,) f32
    float* out = (float*)d_out;
    dim3 grid(NB * CN * YTILES);               // 14336 blocks
    dwconv7x7_sym<<<grid, NTH, 0, stream>>>(x, kv, out);
}

// Round 10
// 365.542 us; speedup vs baseline: 1.2092x; 1.2092x over previous
//
#include <hip/hip_runtime.h>

#define CN 128
#define NB 16
#define KS 7
#define PD 3
#define HW 224
#define NTH 256         // 4 waves
#define RPT 4           // output rows per wave
#define TILE_H 16       // 4 waves x 4 rows
#define YTILES 14       // 224/16

#define LW(i) const float w##i = kv[i];

// FMAs for output row Q with explicit weight scalars.
// Window regs r1..r10 hold input cols x0-3 .. x0+6 of the current input row.
#define FMA_QROW(Q, W0,W1,W2,W3,W4,W5,W6) \
  acx##Q = fmaf(W0, r1,  acx##Q); \
  acx##Q = fmaf(W1, r2,  acx##Q); \
  acx##Q = fmaf(W2, r3,  acx##Q); \
  acx##Q = fmaf(W3, r4,  acx##Q); \
  acx##Q = fmaf(W4, r5,  acx##Q); \
  acx##Q = fmaf(W5, r6,  acx##Q); \
  acx##Q = fmaf(W6, r7,  acx##Q); \
  acy##Q = fmaf(W0, r2,  acy##Q); \
  acy##Q = fmaf(W1, r3,  acy##Q); \
  acy##Q = fmaf(W2, r4,  acy##Q); \
  acy##Q = fmaf(W3, r5,  acy##Q); \
  acy##Q = fmaf(W4, r6,  acy##Q); \
  acy##Q = fmaf(W5, r7,  acy##Q); \
  acy##Q = fmaf(W6, r8,  acy##Q); \
  acz##Q = fmaf(W0, r3,  acz##Q); \
  acz##Q = fmaf(W1, r4,  acz##Q); \
  acz##Q = fmaf(W2, r5,  acz##Q); \
  acz##Q = fmaf(W3, r6,  acz##Q); \
  acz##Q = fmaf(W4, r7,  acz##Q); \
  acz##Q = fmaf(W5, r8,  acz##Q); \
  acz##Q = fmaf(W6, r9,  acz##Q); \
  acw##Q = fmaf(W0, r4,  acw##Q); \
  acw##Q = fmaf(W1, r5,  acw##Q); \
  acw##Q = fmaf(W2, r6,  acw##Q); \
  acw##Q = fmaf(W3, r7,  acw##Q); \
  acw##Q = fmaf(W4, r8,  acw##Q); \
  acw##Q = fmaf(W5, r9,  acw##Q); \
  acw##Q = fmaf(W6, r10, acw##Q);

// Weight rows of the symmetric 7x7 (flat p -> param min(p,48-p)):
#define QROW0(Q) FMA_QROW(Q, w0,w1,w2,w3,w4,w5,w6)
#define QROW1(Q) FMA_QROW(Q, w7,w8,w9,w10,w11,w12,w13)
#define QROW2(Q) FMA_QROW(Q, w14,w15,w16,w17,w18,w19,w20)
#define QROW3(Q) FMA_QROW(Q, w21,w22,w23,w24,w23,w22,w21)
#define QROW4(Q) FMA_QROW(Q, w20,w19,w18,w17,w16,w15,w14)
#define QROW5(Q) FMA_QROW(Q, w13,w12,w11,w10,w9,w8,w7)
#define QROW6(Q) FMA_QROW(Q, w6,w5,w4,w3,w2,w1,w0)

// Window for input row gr0+J straight from global (L1/L2-cached), no LDS.
#define LOAD_ROW(J) { \
    const int gr_ = gr0 + (J); \
    float4 L_ = z4, C_ = z4, R_ = z4; \
    if (gr_ >= 0 && gr_ < HW) { \
        const int off_ = gr_ * HW; \
        L_ = *reinterpret_cast<const float4*>(pl + off_); \
        C_ = *reinterpret_cast<const float4*>(pc + off_); \
        R_ = *reinterpret_cast<const float4*>(pr + off_); \
    } \
    r1 = e0 ? 0.f : L_.y;  r2 = e0 ? 0.f : L_.z;  r3 = e0 ? 0.f : L_.w; \
    r4 = C_.x; r5 = C_.y; r6 = C_.z; r7 = C_.w; \
    r8 = e55 ? 0.f : R_.x; r9 = e55 ? 0.f : R_.y; r10 = e55 ? 0.f : R_.z; }

// hipcc law (rounds 1-9, 6 data points): VGPR cap = 256/min_waves_per_EU; HW
// occupancy steps at 64/128/256 VGPRs. Round 8: demand 140 -> >128 step ->
// 11% occupancy. RPT=4 demand ~80-100; (256,2) caps at 128: no spill AND
// under the 128 step -> 4 waves/SIMD.
__global__ __launch_bounds__(NTH, 2)
void dwconv7x7_sym(const float* __restrict__ x, const float* __restrict__ kv,
                   float* __restrict__ out) {
    const int bid   = blockIdx.x;
    const int plane = bid / YTILES;
    const int ytile = bid - plane * YTILES;
    const int tid   = threadIdx.x;
    const int wave  = tid >> 6;
    const int lane  = tid & 63;
    if (lane >= 56) return;            // no barriers anywhere: early-exit is safe

    const float* xp = x + (size_t)plane * (HW * HW);
    float* op       = out + (size_t)plane * (HW * HW);

    const int row0 = ytile * TILE_H + wave * RPT;  // first output row of strip
    const int gr0  = row0 - PD;                    // first input row needed

    const int x0 = lane * 4;
    const int xl = (x0 >= 4)   ? x0 - 4 : 0;       // clamped left float4
    const int xr = (x0 <= 216) ? x0 + 4 : 220;     // clamped right float4
    const float* pc = xp + x0;
    const float* pl = xp + xl;
    const float* pr = xp + xr;
    const bool e0  = (lane == 0);
    const bool e55 = (lane == 55);
    const float4 z4 = make_float4(0.f, 0.f, 0.f, 0.f);

    LW(0)  LW(1)  LW(2)  LW(3)  LW(4)  LW(5)  LW(6)  LW(7)  LW(8)  LW(9)
    LW(10) LW(11) LW(12) LW(13) LW(14) LW(15) LW(16) LW(17) LW(18) LW(19)
    LW(20) LW(21) LW(22) LW(23) LW(24)

    float acx0=0.f, acy0=0.f, acz0=0.f, acw0=0.f;
    float acx1=0.f, acy1=0.f, acz1=0.f, acw1=0.f;
    float acx2=0.f, acy2=0.f, acz2=0.f, acw2=0.f;
    float acx3=0.f, acy3=0.f, acz3=0.f, acw3=0.f;
    float r1,r2,r3,r4,r5,r6,r7,r8,r9,r10;

    LOAD_ROW(0); QROW0(0);
    LOAD_ROW(1); QROW1(0); QROW0(1);
    LOAD_ROW(2); QROW2(0); QROW1(1); QROW0(2);
    LOAD_ROW(3); QROW3(0); QROW2(1); QROW1(2); QROW0(3);
    LOAD_ROW(4); QROW4(0); QROW3(1); QROW2(2); QROW1(3);
    LOAD_ROW(5); QROW5(0); QROW4(1); QROW3(2); QROW2(3);
    LOAD_ROW(6); QROW6(0); QROW5(1); QROW4(2); QROW3(3);
    LOAD_ROW(7);           QROW6(1); QROW5(2); QROW4(3);
    LOAD_ROW(8);                     QROW6(2); QROW5(3);
    LOAD_ROW(9);                               QROW6(3);

    *reinterpret_cast<float4*>(op + (row0 + 0) * HW + x0) = make_float4(acx0, acy0, acz0, acw0);
    *reinterpret_cast<float4*>(op + (row0 + 1) * HW + x0) = make_float4(acx1, acy1, acz1, acw1);
    *reinterpret_cast<float4*>(op + (row0 + 2) * HW + x0) = make_float4(acx2, acy2, acz2, acw2);
    *reinterpret_cast<float4*>(op + (row0 + 3) * HW + x0) = make_float4(acx3, acy3, acz3, acw3);
}

extern "C" void kernel_launch(void* const* d_in, const int* in_sizes, int n_in,
                              void* d_out, int out_size, void* d_ws, size_t ws_size,
                              hipStream_t stream) {
    const float* x  = (const float*)d_in[0];   // (16,128,224,224) f32
    const float* kv = (const float*)d_in[1];   // (25,) f32
    float* out = (float*)d_out;
    dim3 grid(NB * CN * YTILES);               // 28672 blocks
    dwconv7x7_sym<<<grid, NTH, 0, stream>>>(x, kv, out);
}

// Round 11
// 314.439 us; speedup vs baseline: 1.4057x; 1.1625x over previous
//
#include <hip/hip_runtime.h>

#define CN 128
#define NB 16
#define KS 7
#define PD 3
#define HW 224
#define NTH 256         // 4 waves
#define RPT 4           // output rows per wave
#define TILE_H 16       // 4 waves x 4 rows
#define YT_INT 12       // interior ytiles 1..12
#define LW(i) const float w##i = kv[i];

// FMAs for output row Q with explicit weight scalars.
// Window regs r1..r10 hold input cols x0-3 .. x0+6 of the current input row.
#define FMA_QROW(Q, W0,W1,W2,W3,W4,W5,W6) \
  acx##Q = fmaf(W0, r1,  acx##Q); \
  acx##Q = fmaf(W1, r2,  acx##Q); \
  acx##Q = fmaf(W2, r3,  acx##Q); \
  acx##Q = fmaf(W3, r4,  acx##Q); \
  acx##Q = fmaf(W4, r5,  acx##Q); \
  acx##Q = fmaf(W5, r6,  acx##Q); \
  acx##Q = fmaf(W6, r7,  acx##Q); \
  acy##Q = fmaf(W0, r2,  acy##Q); \
  acy##Q = fmaf(W1, r3,  acy##Q); \
  acy##Q = fmaf(W2, r4,  acy##Q); \
  acy##Q = fmaf(W3, r5,  acy##Q); \
  acy##Q = fmaf(W4, r6,  acy##Q); \
  acy##Q = fmaf(W5, r7,  acy##Q); \
  acy##Q = fmaf(W6, r8,  acy##Q); \
  acz##Q = fmaf(W0, r3,  acz##Q); \
  acz##Q = fmaf(W1, r4,  acz##Q); \
  acz##Q = fmaf(W2, r5,  acz##Q); \
  acz##Q = fmaf(W3, r6,  acz##Q); \
  acz##Q = fmaf(W4, r7,  acz##Q); \
  acz##Q = fmaf(W5, r8,  acz##Q); \
  acz##Q = fmaf(W6, r9,  acz##Q); \
  acw##Q = fmaf(W0, r4,  acw##Q); \
  acw##Q = fmaf(W1, r5,  acw##Q); \
  acw##Q = fmaf(W2, r6,  acw##Q); \
  acw##Q = fmaf(W3, r7,  acw##Q); \
  acw##Q = fmaf(W4, r8,  acw##Q); \
  acw##Q = fmaf(W5, r9,  acw##Q); \
  acw##Q = fmaf(W6, r10, acw##Q);

// Weight rows of the symmetric 7x7 (flat p -> param min(p,48-p)):
#define QROW0(Q) FMA_QROW(Q, w0,w1,w2,w3,w4,w5,w6)
#define QROW1(Q) FMA_QROW(Q, w7,w8,w9,w10,w11,w12,w13)
#define QROW2(Q) FMA_QROW(Q, w14,w15,w16,w17,w18,w19,w20)
#define QROW3(Q) FMA_QROW(Q, w21,w22,w23,w24,w23,w22,w21)
#define QROW4(Q) FMA_QROW(Q, w20,w19,w18,w17,w16,w15,w14)
#define QROW5(Q) FMA_QROW(Q, w13,w12,w11,w10,w9,w8,w7)
#define QROW6(Q) FMA_QROW(Q, w6,w5,w4,w3,w2,w1,w0)

// UNCONDITIONAL loads (pipelinable). EDGE tiles clamp the row pointer and
// multiply by a wave-uniform 0/1 mask AFTER the load; interior tiles fold
// grc_=gr_, m_=1.0 at compile time -> raw loads, zero overhead.
#define LOAD_ROW(J) { \
    const int gr_ = gr0 + (J); \
    const int grc_ = EDGE ? (gr_ < 0 ? 0 : (gr_ > HW-1 ? HW-1 : gr_)) : gr_; \
    const float m_ = EDGE ? ((gr_ == grc_) ? 1.f : 0.f) : 1.f; \
    const int off_ = grc_ * HW; \
    const float4 L_ = *reinterpret_cast<const float4*>(pl + off_); \
    const float4 C_ = *reinterpret_cast<const float4*>(pc + off_); \
    const float4 R_ = *reinterpret_cast<const float4*>(pr + off_); \
    r1 = e0 ? 0.f : L_.y*m_;  r2 = e0 ? 0.f : L_.z*m_;  r3 = e0 ? 0.f : L_.w*m_; \
    r4 = C_.x*m_; r5 = C_.y*m_; r6 = C_.z*m_; r7 = C_.w*m_; \
    r8 = e55 ? 0.f : R_.x*m_; r9 = e55 ? 0.f : R_.y*m_; r10 = e55 ? 0.f : R_.z*m_; }

// hipcc law (6 data points, rounds 1-9): VGPR cap = 256/min_waves_per_EU;
// HW occupancy steps at 64/128/256. (256,2) -> cap 128: no spill (demand
// ~105-125) and under the 128 step -> 4 waves/SIMD.
template<bool EDGE>
__global__ __launch_bounds__(NTH, 2)
void dwconv7x7_sym(const float* __restrict__ x, const float* __restrict__ kv,
                   float* __restrict__ out) {
    const int bid = blockIdx.x;
    int plane, ytile;
    if (EDGE) {
        plane = bid >> 1;
        ytile = (bid & 1) * 13;           // ytile 0 or 13
    } else {
        plane = bid / YT_INT;
        ytile = 1 + (bid - plane * YT_INT);  // ytiles 1..12: rows always in range
    }
    const int tid  = threadIdx.x;
    const int wave = tid >> 6;
    const int lane = tid & 63;
    if (lane >= 56) return;            // no barriers anywhere: early-exit is safe

    const float* xp = x + (size_t)plane * (HW * HW);
    float* op       = out + (size_t)plane * (HW * HW);

    const int row0 = ytile * TILE_H + wave * RPT;  // first output row of strip
    const int gr0  = row0 - PD;                    // first input row needed

    const int x0 = lane * 4;
    const int xl = (x0 >= 4)   ? x0 - 4 : 0;       // clamped left float4
    const int xr = (x0 <= 216) ? x0 + 4 : 220;     // clamped right float4
    const float* pc = xp + x0;
    const float* pl = xp + xl;
    const float* pr = xp + xr;
    const bool e0  = (lane == 0);
    const bool e55 = (lane == 55);

    LW(0)  LW(1)  LW(2)  LW(3)  LW(4)  LW(5)  LW(6)  LW(7)  LW(8)  LW(9)
    LW(10) LW(11) LW(12) LW(13) LW(14) LW(15) LW(16) LW(17) LW(18) LW(19)
    LW(20) LW(21) LW(22) LW(23) LW(24)

    float acx0=0.f, acy0=0.f, acz0=0.f, acw0=0.f;
    float acx1=0.f, acy1=0.f, acz1=0.f, acw1=0.f;
    float acx2=0.f, acy2=0.f, acz2=0.f, acw2=0.f;
    float acx3=0.f, acy3=0.f, acz3=0.f, acw3=0.f;
    float r1,r2,r3,r4,r5,r6,r7,r8,r9,r10;

    LOAD_ROW(0); QROW0(0);
    LOAD_ROW(1); QROW1(0); QROW0(1);
    LOAD_ROW(2); QROW2(0); QROW1(1); QROW0(2);
    LOAD_ROW(3); QROW3(0); QROW2(1); QROW1(2); QROW0(3);
    LOAD_ROW(4); QROW4(0); QROW3(1); QROW2(2); QROW1(3);
    LOAD_ROW(5); QROW5(0); QROW4(1); QROW3(2); QROW2(3);
    LOAD_ROW(6); QROW6(0); QROW5(1); QROW4(2); QROW3(3);
    LOAD_ROW(7);           QROW6(1); QROW5(2); QROW4(3);
    LOAD_ROW(8);                     QROW6(2); QROW5(3);
    LOAD_ROW(9);                               QROW6(3);

    *reinterpret_cast<float4*>(op + (row0 + 0) * HW + x0) = make_float4(acx0, acy0, acz0, acw0);
    *reinterpret_cast<float4*>(op + (row0 + 1) * HW + x0) = make_float4(acx1, acy1, acz1, acw1);
    *reinterpret_cast<float4*>(op + (row0 + 2) * HW + x0) = make_float4(acx2, acy2, acz2, acw2);
    *reinterpret_cast<float4*>(op + (row0 + 3) * HW + x0) = make_float4(acx3, acy3, acz3, acw3);
}

extern "C" void kernel_launch(void* const* d_in, const int* in_sizes, int n_in,
                              void* d_out, int out_size, void* d_ws, size_t ws_size,
                              hipStream_t stream) {
    const float* x  = (const float*)d_in[0];   // (16,128,224,224) f32
    const float* kv = (const float*)d_in[1];   // (25,) f32
    float* out = (float*)d_out;
    dwconv7x7_sym<false><<<NB * CN * YT_INT, NTH, 0, stream>>>(x, kv, out); // 24576 blocks
    dwconv7x7_sym<true ><<<NB * CN * 2,      NTH, 0, stream>>>(x, kv, out); //  4096 blocks
}

// Round 12
// 306.186 us; speedup vs baseline: 1.4436x; 1.0270x over previous
//
#include <hip/hip_runtime.h>

#define CN 128
#define NB 16
#define KS 7
#define PD 3
#define HW 224
#define NTH 256         // 4 waves
#define RPT 4           // output rows per wave
#define TILE_H 16       // 4 waves x 4 rows
#define YT_INT 12       // interior ytiles 1..12
#define LW(i) const float w##i = kv[i];

// FMAs for output row Q with explicit weight scalars.
// Window regs r1..r10 hold input cols x0-3 .. x0+6 of the current input row.
#define FMA_QROW(Q, W0,W1,W2,W3,W4,W5,W6) \
  acx##Q = fmaf(W0, r1,  acx##Q); \
  acx##Q = fmaf(W1, r2,  acx##Q); \
  acx##Q = fmaf(W2, r3,  acx##Q); \
  acx##Q = fmaf(W3, r4,  acx##Q); \
  acx##Q = fmaf(W4, r5,  acx##Q); \
  acx##Q = fmaf(W5, r6,  acx##Q); \
  acx##Q = fmaf(W6, r7,  acx##Q); \
  acy##Q = fmaf(W0, r2,  acy##Q); \
  acy##Q = fmaf(W1, r3,  acy##Q); \
  acy##Q = fmaf(W2, r4,  acy##Q); \
  acy##Q = fmaf(W3, r5,  acy##Q); \
  acy##Q = fmaf(W4, r6,  acy##Q); \
  acy##Q = fmaf(W5, r7,  acy##Q); \
  acy##Q = fmaf(W6, r8,  acy##Q); \
  acz##Q = fmaf(W0, r3,  acz##Q); \
  acz##Q = fmaf(W1, r4,  acz##Q); \
  acz##Q = fmaf(W2, r5,  acz##Q); \
  acz##Q = fmaf(W3, r6,  acz##Q); \
  acz##Q = fmaf(W4, r7,  acz##Q); \
  acz##Q = fmaf(W5, r8,  acz##Q); \
  acz##Q = fmaf(W6, r9,  acz##Q); \
  acw##Q = fmaf(W0, r4,  acw##Q); \
  acw##Q = fmaf(W1, r5,  acw##Q); \
  acw##Q = fmaf(W2, r6,  acw##Q); \
  acw##Q = fmaf(W3, r7,  acw##Q); \
  acw##Q = fmaf(W4, r8,  acw##Q); \
  acw##Q = fmaf(W5, r9,  acw##Q); \
  acw##Q = fmaf(W6, r10, acw##Q);

// Weight rows of the symmetric 7x7 (flat p -> param min(p,48-p)):
#define QROW0(Q) FMA_QROW(Q, w0,w1,w2,w3,w4,w5,w6)
#define QROW1(Q) FMA_QROW(Q, w7,w8,w9,w10,w11,w12,w13)
#define QROW2(Q) FMA_QROW(Q, w14,w15,w16,w17,w18,w19,w20)
#define QROW3(Q) FMA_QROW(Q, w21,w22,w23,w24,w23,w22,w21)
#define QROW4(Q) FMA_QROW(Q, w20,w19,w18,w17,w16,w15,w14)
#define QROW5(Q) FMA_QROW(Q, w13,w12,w11,w10,w9,w8,w7)
#define QROW6(Q) FMA_QROW(Q, w6,w5,w4,w3,w2,w1,w0)

// 4-deep software pipeline: ISSUE(S,J) starts row J's 3 unconditional loads
// into named register set S; EXTRACT(S) converts set S to window regs when
// the FMAs need them (3 steps of FMAs cover the load latency). EDGE tiles
// clamp the row pointer and mask AFTER the load; interior folds to raw loads.
#define DECL_SET(S) float4 L##S, C##S, R##S; float m##S;
#define ISSUE(S, J) { \
    const int gr_ = gr0 + (J); \
    const int grc_ = EDGE ? (gr_ < 0 ? 0 : (gr_ > HW-1 ? HW-1 : gr_)) : gr_; \
    m##S = EDGE ? ((gr_ == grc_) ? 1.f : 0.f) : 1.f; \
    const int off_ = grc_ * HW; \
    L##S = *reinterpret_cast<const float4*>(pl + off_); \
    C##S = *reinterpret_cast<const float4*>(pc + off_); \
    R##S = *reinterpret_cast<const float4*>(pr + off_); }
#define EXTRACT(S) { \
    r1 = e0 ? 0.f : L##S.y*m##S;  r2 = e0 ? 0.f : L##S.z*m##S;  r3 = e0 ? 0.f : L##S.w*m##S; \
    r4 = C##S.x*m##S; r5 = C##S.y*m##S; r6 = C##S.z*m##S; r7 = C##S.w*m##S; \
    r8 = e55 ? 0.f : R##S.x*m##S; r9 = e55 ? 0.f : R##S.y*m##S; r10 = e55 ? 0.f : R##S.z*m##S; }

// hipcc law (rounds 1-9, 6 points): VGPR cap = 256/min_waves_per_EU; HW
// occupancy steps at 64/128/256. (256,2) -> cap 128. Pipeline demand ~90-105.
template<bool EDGE>
__global__ __launch_bounds__(NTH, 2)
void dwconv7x7_sym(const float* __restrict__ x, const float* __restrict__ kv,
                   float* __restrict__ out) {
    const int bid = blockIdx.x;
    int plane, ytile;
    if (EDGE) {
        plane = bid >> 1;
        ytile = (bid & 1) * 13;              // ytile 0 or 13
    } else {
        plane = bid / YT_INT;
        ytile = 1 + (bid - plane * YT_INT);  // ytiles 1..12: rows always in range
    }
    const int tid  = threadIdx.x;
    const int wave = tid >> 6;
    const int lane = tid & 63;
    if (lane >= 56) return;            // no barriers anywhere: early-exit is safe

    const float* xp = x + (size_t)plane * (HW * HW);
    float* op       = out + (size_t)plane * (HW * HW);

    const int row0 = ytile * TILE_H + wave * RPT;  // first output row of strip
    const int gr0  = row0 - PD;                    // first input row needed

    const int x0 = lane * 4;
    const int xl = (x0 >= 4)   ? x0 - 4 : 0;       // clamped left float4
    const int xr = (x0 <= 216) ? x0 + 4 : 220;     // clamped right float4
    const float* pc = xp + x0;
    const float* pl = xp + xl;
    const float* pr = xp + xr;
    const bool e0  = (lane == 0);
    const bool e55 = (lane == 55);

    LW(0)  LW(1)  LW(2)  LW(3)  LW(4)  LW(5)  LW(6)  LW(7)  LW(8)  LW(9)
    LW(10) LW(11) LW(12) LW(13) LW(14) LW(15) LW(16) LW(17) LW(18) LW(19)
    LW(20) LW(21) LW(22) LW(23) LW(24)

    float acx0=0.f, acy0=0.f, acz0=0.f, acw0=0.f;
    float acx1=0.f, acy1=0.f, acz1=0.f, acw1=0.f;
    float acx2=0.f, acy2=0.f, acz2=0.f, acw2=0.f;
    float acx3=0.f, acy3=0.f, acz3=0.f, acw3=0.f;
    float r1,r2,r3,r4,r5,r6,r7,r8,r9,r10;
    DECL_SET(A) DECL_SET(B) DECL_SET(C) DECL_SET(D)

    // prologue: 4 rows in flight
    ISSUE(A,0) ISSUE(B,1) ISSUE(C,2) ISSUE(D,3)
    // steady state: consume row J (set), refill with row J+4
    EXTRACT(A) QROW0(0);                                     ISSUE(A,4)
    EXTRACT(B) QROW1(0); QROW0(1);                           ISSUE(B,5)
    EXTRACT(C) QROW2(0); QROW1(1); QROW0(2);                 ISSUE(C,6)
    EXTRACT(D) QROW3(0); QROW2(1); QROW1(2); QROW0(3);       ISSUE(D,7)
    EXTRACT(A) QROW4(0); QROW3(1); QROW2(2); QROW1(3);       ISSUE(A,8)
    EXTRACT(B) QROW5(0); QROW4(1); QROW3(2); QROW2(3);       ISSUE(B,9)
    EXTRACT(C) QROW6(0); QROW5(1); QROW4(2); QROW3(3);
    EXTRACT(D)           QROW6(1); QROW5(2); QROW4(3);
    EXTRACT(A)                     QROW6(2); QROW5(3);
    EXTRACT(B)                               QROW6(3);

    *reinterpret_cast<float4*>(op + (row0 + 0) * HW + x0) = make_float4(acx0, acy0, acz0, acw0);
    *reinterpret_cast<float4*>(op + (row0 + 1) * HW + x0) = make_float4(acx1, acy1, acz1, acw1);
    *reinterpret_cast<float4*>(op + (row0 + 2) * HW + x0) = make_float4(acx2, acy2, acz2, acw2);
    *reinterpret_cast<float4*>(op + (row0 + 3) * HW + x0) = make_float4(acx3, acy3, acz3, acw3);
}

extern "C" void kernel_launch(void* const* d_in, const int* in_sizes, int n_in,
                              void* d_out, int out_size, void* d_ws, size_t ws_size,
                              hipStream_t stream) {
    const float* x  = (const float*)d_in[0];   // (16,128,224,224) f32
    const float* kv = (const float*)d_in[1];   // (25,) f32
    float* out = (float*)d_out;
    dwconv7x7_sym<false><<<NB * CN * YT_INT, NTH, 0, stream>>>(x, kv, out); // 24576 blocks
    dwconv7x7_sym<true ><<<NB * CN * 2,      NTH, 0, stream>>>(x, kv, out); //  4096 blocks
}